// Round 12
// baseline (771.970 us; speedup 1.0000x reference)
//
#include <hip/hip_runtime.h>
#include <hip/hip_bf16.h>

#define NDIN 128
#define NDOUT 64
#define BR 256        // rows per GEMM block
#define KC 16         // k-chunk staged in LDS
#define BSH 6         // log2(nodes per bucket)
#define BNODES 64     // nodes per bucket
#define HB 256        // histogram / place blocks
#define NBUCK_MAX 2048
#define DMASK 0xFFFFF // low 20 bits: dst (< 2^17); bits 20-25: src&63

// ---------------------------------------------------------------------------
// Fused K1: role-split mega-kernel.
//   blocks [0, gblocks)      : xw = bf16(x @ W) tile (VALU/LDS-bound)
//   blocks [gblocks, +HB)    : bucket histogram via LDS (NO global atomics)
// Bucket = src>>6 (64 nodes). Per-block LDS hist -> coalesced partial flush.
// partial[b*HB + hb] = count of block hb's edges in bucket b.
// ---------------------------------------------------------------------------
__global__ __launch_bounds__(256) void gemm_hist_kernel(
    const float* __restrict__ x, const float* __restrict__ w,
    __hip_bfloat16* __restrict__ xw, int n_nodes, int gblocks,
    const int* __restrict__ src, int* __restrict__ partial, int n_edges,
    int nbuck, int ch) {
  __shared__ float wlds[NDIN][NDOUT];  // 32 KB (gemm); reused as hist (hist)
  __shared__ float xt[KC][BR];         // 16 KB (gemm only)
  const int t = threadIdx.x;

  if ((int)blockIdx.x >= gblocks) {
    // ---- bucket-hist role ----
    int* hist = (int*)&wlds[0][0];  // nbuck <= NBUCK_MAX=2048 ints <= 8 KB
    for (int i = t; i < nbuck; i += 256) hist[i] = 0;
    __syncthreads();
    const int hb = blockIdx.x - gblocks;
    const int e0 = hb * ch;
    const int e1 = min(e0 + ch, n_edges);
    for (int e = e0 + t * 4; e < e1; e += 256 * 4) {
      if (e + 4 <= e1) {
        const int4 s4 = *(const int4*)(src + e);
        atomicAdd(&hist[s4.x >> BSH], 1);
        atomicAdd(&hist[s4.y >> BSH], 1);
        atomicAdd(&hist[s4.z >> BSH], 1);
        atomicAdd(&hist[s4.w >> BSH], 1);
      } else {
        for (int k = e; k < e1; ++k) atomicAdd(&hist[src[k] >> BSH], 1);
      }
    }
    __syncthreads();
    for (int i = t; i < nbuck; i += 256) partial[(size_t)i * HB + hb] = hist[i];
    return;
  }

  // ---- gemm role ----
  const float4* w4 = (const float4*)w;
  float4* wl4 = (float4*)(&wlds[0][0]);
#pragma unroll
  for (int i = 0; i < (NDIN * NDOUT / 4) / 256; ++i)
    wl4[t + i * 256] = w4[t + i * 256];

  const int row0 = blockIdx.x * BR;
  const int colg = t & 7;
  const int rowg = t >> 3;

  float acc[8][8];
#pragma unroll
  for (int i = 0; i < 8; ++i)
#pragma unroll
    for (int j = 0; j < 8; ++j) acc[i][j] = 0.f;

  for (int kc = 0; kc < NDIN; kc += KC) {
    __syncthreads();
#pragma unroll
    for (int p = 0; p < 4; ++p) {
      const int i = t + p * 256;
      const int r = i >> 2;
      const int c4 = i & 3;
      const int grow = row0 + r;
      float4 v = (grow < n_nodes)
                     ? *(const float4*)(x + (size_t)grow * NDIN + kc + c4 * 4)
                     : make_float4(0.f, 0.f, 0.f, 0.f);
      xt[c4 * 4 + 0][r] = v.x;
      xt[c4 * 4 + 1][r] = v.y;
      xt[c4 * 4 + 2][r] = v.z;
      xt[c4 * 4 + 3][r] = v.w;
    }
    __syncthreads();
#pragma unroll
    for (int k = 0; k < KC; ++k) {
      const float4 a0 = *(const float4*)(&xt[k][rowg * 8]);
      const float4 a1 = *(const float4*)(&xt[k][rowg * 8 + 4]);
      const float4 b0 = *(const float4*)(&wlds[kc + k][colg * 8]);
      const float4 b1 = *(const float4*)(&wlds[kc + k][colg * 8 + 4]);
      const float a[8] = {a0.x, a0.y, a0.z, a0.w, a1.x, a1.y, a1.z, a1.w};
      const float b[8] = {b0.x, b0.y, b0.z, b0.w, b1.x, b1.y, b1.z, b1.w};
#pragma unroll
      for (int i = 0; i < 8; ++i)
#pragma unroll
        for (int j = 0; j < 8; ++j) acc[i][j] += a[i] * b[j];
    }
  }
#pragma unroll
  for (int i = 0; i < 8; ++i) {
    const int grow = row0 + rowg * 8 + i;
    if (grow < n_nodes) {
      __hip_bfloat16 tmp[8];
#pragma unroll
      for (int j = 0; j < 8; ++j) tmp[j] = __float2bfloat16(acc[i][j]);
      *(uint4*)(xw + (size_t)grow * NDOUT + colg * 8) = *(const uint4*)tmp;
    }
  }
}

// ---------------------------------------------------------------------------
// Exclusive scan of partial (nbuck*HB ints, bucket-major) -> sc (3 kernels)
// ---------------------------------------------------------------------------
__global__ __launch_bounds__(1024) void scan_block_kernel(
    const int* __restrict__ partial, int* __restrict__ sc,
    int* __restrict__ bsums, int n) {
  __shared__ int s[1024];
  const int t = threadIdx.x;
  const int i = blockIdx.x * 1024 + t;
  const int v = (i < n) ? partial[i] : 0;
  s[t] = v;
  __syncthreads();
#pragma unroll
  for (int off = 1; off < 1024; off <<= 1) {
    int add = (t >= off) ? s[t - off] : 0;
    __syncthreads();
    s[t] += add;
    __syncthreads();
  }
  if (i < n) sc[i] = s[t] - v;  // exclusive
  if (t == 1023) bsums[blockIdx.x] = s[1023];
}

__global__ __launch_bounds__(1024) void scan_tops_kernel(int* __restrict__ bsums,
                                                         int nb) {
  __shared__ int s[1024];
  const int t = threadIdx.x;
  const int v = (t < nb) ? bsums[t] : 0;
  s[t] = v;
  __syncthreads();
#pragma unroll
  for (int off = 1; off < 1024; off <<= 1) {
    int add = (t >= off) ? s[t - off] : 0;
    __syncthreads();
    s[t] += add;
    __syncthreads();
  }
  if (t < nb) bsums[t] = s[t] - v;
}

__global__ __launch_bounds__(256) void add_off_kernel(
    int* __restrict__ sc, const int* __restrict__ bsums, int n) {
  const int i = blockIdx.x * 256 + threadIdx.x;
  if (i < n) sc[i] += bsums[i >> 10];
}

// ---------------------------------------------------------------------------
// K3: place. Same edge->block assignment as hist role. Per-block segment
// bases loaded into LDS; slot = LDS atomicAdd (order within a (bucket,block)
// segment is irrelevant -- aggregation is commutative). Only the 8B bins
// store is scattered, and it lands in bucket-grouped order.
// ---------------------------------------------------------------------------
__global__ __launch_bounds__(256) void place_kernel(
    const int* __restrict__ src, const int* __restrict__ dst,
    const float* __restrict__ ew, const int* __restrict__ sc,
    int2* __restrict__ bins, int n_edges, int nbuck, int ch) {
  __shared__ int lbase[NBUCK_MAX];
  const int t = threadIdx.x;
  const int hb = blockIdx.x;
  for (int i = t; i < nbuck; i += 256) lbase[i] = sc[(size_t)i * HB + hb];
  __syncthreads();
  const int e0 = hb * ch;
  const int e1 = min(e0 + ch, n_edges);
  for (int e = e0 + t * 4; e < e1; e += 256 * 4) {
    if (e + 4 <= e1) {
      const int4 s4 = *(const int4*)(src + e);
      const int4 d4 = *(const int4*)(dst + e);
      const float4 w4 = *(const float4*)(ew + e);
      const int p0 = atomicAdd(&lbase[s4.x >> BSH], 1);
      const int p1 = atomicAdd(&lbase[s4.y >> BSH], 1);
      const int p2 = atomicAdd(&lbase[s4.z >> BSH], 1);
      const int p3 = atomicAdd(&lbase[s4.w >> BSH], 1);
      bins[p0] = make_int2(d4.x | ((s4.x & 63) << 20), __float_as_int(w4.x));
      bins[p1] = make_int2(d4.y | ((s4.y & 63) << 20), __float_as_int(w4.y));
      bins[p2] = make_int2(d4.z | ((s4.z & 63) << 20), __float_as_int(w4.z));
      bins[p3] = make_int2(d4.w | ((s4.w & 63) << 20), __float_as_int(w4.w));
    } else {
      for (int k = e; k < e1; ++k) {
        const int s = src[k];
        const int p = atomicAdd(&lbase[s >> BSH], 1);
        bins[p] = make_int2(dst[k] | ((s & 63) << 20), __float_as_int(ew[k]));
      }
    }
  }
}

// ---------------------------------------------------------------------------
// K4: aggregate. One block per bucket (64 nodes). Edges read sequentially;
// xw gathers 8 in flight; LDS-atomic f32 accumulate into [64][64] tile;
// coalesced ReLU'd tile write. Covers every output element (no memset).
// ---------------------------------------------------------------------------
__global__ __launch_bounds__(256) void aggregate_kernel(
    const __hip_bfloat16* __restrict__ xw, const int2* __restrict__ bins,
    const int* __restrict__ sc, float* __restrict__ out, int n_nodes,
    int n_edges, int nbuck) {
  __shared__ float tile[BNODES][NDOUT];  // 16 KB
  const int t = threadIdx.x;
  const int b = blockIdx.x;
  // zero tile: 4096 floats, 16 per thread
  float4* tf = (float4*)&tile[0][0];
#pragma unroll
  for (int k = 0; k < 4; ++k)
    tf[t * 4 + k] = make_float4(0.f, 0.f, 0.f, 0.f);
  __syncthreads();

  const int start = sc[(size_t)b * HB];
  const int end = (b == nbuck - 1) ? n_edges : sc[(size_t)(b + 1) * HB];
  const int lane = t & 63;
  const int wv = t >> 6;  // 4 waves split the bucket's edges
  const int cnt = end - start;
  const int q = (cnt + 3) >> 2;
  const int ws = start + wv * q;
  const int we = min(ws + q, end);

  int i = ws;
  for (; i + 8 <= we; i += 8) {
    int2 bb[8];
#pragma unroll
    for (int j = 0; j < 8; ++j) bb[j] = bins[i + j];
    float v[8];
#pragma unroll
    for (int j = 0; j < 8; ++j)
      v[j] = __bfloat162float(
          xw[(size_t)(bb[j].x & DMASK) * NDOUT + lane]);
#pragma unroll
    for (int j = 0; j < 8; ++j)
      atomicAdd(&tile[(bb[j].x >> 20) & 63][lane],
                __int_as_float(bb[j].y) * v[j]);
  }
  for (; i < we; ++i) {
    const int2 bb = bins[i];
    const float v =
        __bfloat162float(xw[(size_t)(bb.x & DMASK) * NDOUT + lane]);
    atomicAdd(&tile[(bb.x >> 20) & 63][lane], __int_as_float(bb.y) * v);
  }
  __syncthreads();

  // write tile: thread t -> row t/4, cols (t&3)*16 .. +15 (coalesced)
  const int r = t >> 2;
  const int c0 = (t & 3) * 16;
  const int gnode = b * BNODES + r;
  if (gnode < n_nodes) {
    float* dstp = out + (size_t)gnode * NDOUT + c0;
#pragma unroll
    for (int k = 0; k < 4; ++k) {
      float4 v = *(const float4*)(&tile[r][c0 + k * 4]);
      v.x = fmaxf(v.x, 0.f);
      v.y = fmaxf(v.y, 0.f);
      v.z = fmaxf(v.z, 0.f);
      v.w = fmaxf(v.w, 0.f);
      *(float4*)(dstp + k * 4) = v;
    }
  }
}

// ---------------------------------------------------------------------------
// Fallback path (ws too small / too many buckets): atomic scatter + relu
// ---------------------------------------------------------------------------
__global__ __launch_bounds__(256) void edge_scatter_kernel(
    const __hip_bfloat16* __restrict__ xw, const float* __restrict__ ew,
    const int* __restrict__ src, const int* __restrict__ dst,
    float* __restrict__ out, int n_edges) {
  const int lane = threadIdx.x & 63;
  const int wid = (blockIdx.x * 256 + threadIdx.x) >> 6;
  const int nw = (gridDim.x * 256) >> 6;
  for (int e0 = wid * 4; e0 < n_edges; e0 += nw * 4) {
    int s[4];
    float v[4];
    bool ok[4];
#pragma unroll
    for (int j = 0; j < 4; ++j) {
      const int e = e0 + j;
      ok[j] = (e < n_edges);
      const int ee = ok[j] ? e : 0;
      s[j] = src[ee];
      v[j] = __bfloat162float(xw[(size_t)dst[ee] * NDOUT + lane]) * ew[ee];
    }
#pragma unroll
    for (int j = 0; j < 4; ++j) {
      if (ok[j]) unsafeAtomicAdd(out + (size_t)s[j] * NDOUT + lane, v[j]);
    }
  }
}

__global__ __launch_bounds__(256) void relu_kernel(float* __restrict__ out,
                                                   int n4) {
  float4* o4 = (float4*)out;
  int i = blockIdx.x * 256 + threadIdx.x;
  const int stride = gridDim.x * 256;
  for (; i < n4; i += stride) {
    float4 v = o4[i];
    v.x = fmaxf(v.x, 0.f);
    v.y = fmaxf(v.y, 0.f);
    v.z = fmaxf(v.z, 0.f);
    v.w = fmaxf(v.w, 0.f);
    o4[i] = v;
  }
}

extern "C" void kernel_launch(void* const* d_in, const int* in_sizes, int n_in,
                              void* d_out, int out_size, void* d_ws,
                              size_t ws_size, hipStream_t stream) {
  const float* x = (const float*)d_in[0];     // [N, 128]
  const float* ew = (const float*)d_in[1];    // [E]
  const float* w = (const float*)d_in[2];     // [128, 64]
  const int* esrc = (const int*)d_in[3];      // [E]
  const int* edst = (const int*)d_in[4];      // [E]
  float* out = (float*)d_out;                 // [N, 64]

  const int n_nodes = in_sizes[0] / NDIN;
  const int n_edges = in_sizes[1];
  const int nbuck = (n_nodes + BNODES - 1) >> BSH;
  const int ch = (((n_edges + HB - 1) / HB) + 3) & ~3;  // 4-aligned chunk
  const int nscan = nbuck * HB;

  // ws layout:
  //   xw:      N*64 bf16
  //   bins:    E int2  ({dst | (src&63)<<20, ew})
  //   partial: nbuck*HB int
  //   sc:      nbuck*HB int
  //   bsums:   1024 int
  char* base = (char*)d_ws;
  size_t off = 0;
  __hip_bfloat16* xw = (__hip_bfloat16*)(base + off);
  off += (size_t)n_nodes * NDOUT * 2;
  off = (off + 15) & ~(size_t)15;
  int2* bins = (int2*)(base + off); off += (size_t)n_edges * 8;
  int* partial = (int*)(base + off); off += (size_t)nscan * 4;
  int* sc = (int*)(base + off); off += (size_t)nscan * 4;
  int* bsums = (int*)(base + off); off += 4096;
  const bool csr_ok = (ws_size >= off) && (nbuck <= NBUCK_MAX) &&
                      (n_nodes <= DMASK);

  const int gblocks = (n_nodes + BR - 1) / BR;

  if (csr_ok) {
    // 1) fused GEMM + bucket-hist (no global atomics anywhere)
    gemm_hist_kernel<<<gblocks + HB, 256, 0, stream>>>(
        x, w, xw, n_nodes, gblocks, esrc, partial, n_edges, nbuck, ch);
    // 2) scan partials -> segment bases
    const int nb = (nscan + 1023) / 1024;
    scan_block_kernel<<<nb, 1024, 0, stream>>>(partial, sc, bsums, nscan);
    scan_tops_kernel<<<1, 1024, 0, stream>>>(bsums, nb);
    add_off_kernel<<<(nscan + 255) / 256, 256, 0, stream>>>(sc, bsums, nscan);
    // 3) place into bucket-grouped bins (LDS-atomic slots)
    place_kernel<<<HB, 256, 0, stream>>>(esrc, edst, ew, sc, bins, n_edges,
                                         nbuck, ch);
    // 4) aggregate per bucket + ReLU (writes every output element)
    aggregate_kernel<<<nbuck, 256, 0, stream>>>(xw, bins, sc, out, n_nodes,
                                                n_edges, nbuck);
  } else {
    gemm_hist_kernel<<<gblocks, 256, 0, stream>>>(
        x, w, xw, n_nodes, gblocks, esrc, (int*)d_out, n_edges, 0, ch);
    hipMemsetAsync(d_out, 0, (size_t)out_size * sizeof(float), stream);
    edge_scatter_kernel<<<2048, 256, 0, stream>>>(xw, ew, esrc, edst, out,
                                                  n_edges);
    relu_kernel<<<1024, 256, 0, stream>>>(out, out_size / 4);
  }
}

// Round 13
// 226.188 us; speedup vs baseline: 3.4130x; 3.4130x over previous
//
#include <hip/hip_runtime.h>
#include <hip/hip_bf16.h>

#define NDIN 128
#define NDOUT 64
#define BR 256        // rows per GEMM block
#define KC 16         // k-chunk staged in LDS
#define BSH 6         // log2(nodes per bucket)
#define BNODES 64     // nodes per bucket
#define HB 256        // histogram / place blocks
#define NBUCK_MAX 2048
#define DMASK 0xFFFFF // low 20 bits: dst (< 2^17); bits 20-25: src&63
#define CAP 2048      // edges per LDS chunk in bucket_agg (16 KB)

// ---------------------------------------------------------------------------
// Fused K1: role-split mega-kernel. (proven in round 12)
//   blocks [0, gblocks)      : xw = bf16(x @ W) tile (VALU/LDS-bound)
//   blocks [gblocks, +HB)    : bucket histogram via LDS (NO global atomics)
// ---------------------------------------------------------------------------
__global__ __launch_bounds__(256) void gemm_hist_kernel(
    const float* __restrict__ x, const float* __restrict__ w,
    __hip_bfloat16* __restrict__ xw, int n_nodes, int gblocks,
    const int* __restrict__ src, int* __restrict__ partial, int n_edges,
    int nbuck, int ch) {
  __shared__ float wlds[NDIN][NDOUT];  // 32 KB (gemm); reused as hist (hist)
  __shared__ float xt[KC][BR];         // 16 KB (gemm only)
  const int t = threadIdx.x;

  if ((int)blockIdx.x >= gblocks) {
    // ---- bucket-hist role (LDS int atomics only) ----
    int* hist = (int*)&wlds[0][0];
    for (int i = t; i < nbuck; i += 256) hist[i] = 0;
    __syncthreads();
    const int hb = blockIdx.x - gblocks;
    const int e0 = hb * ch;
    const int e1 = min(e0 + ch, n_edges);
    for (int e = e0 + t * 4; e < e1; e += 256 * 4) {
      if (e + 4 <= e1) {
        const int4 s4 = *(const int4*)(src + e);
        atomicAdd(&hist[s4.x >> BSH], 1);
        atomicAdd(&hist[s4.y >> BSH], 1);
        atomicAdd(&hist[s4.z >> BSH], 1);
        atomicAdd(&hist[s4.w >> BSH], 1);
      } else {
        for (int k = e; k < e1; ++k) atomicAdd(&hist[src[k] >> BSH], 1);
      }
    }
    __syncthreads();
    for (int i = t; i < nbuck; i += 256) partial[(size_t)i * HB + hb] = hist[i];
    return;
  }

  // ---- gemm role ----
  const float4* w4 = (const float4*)w;
  float4* wl4 = (float4*)(&wlds[0][0]);
#pragma unroll
  for (int i = 0; i < (NDIN * NDOUT / 4) / 256; ++i)
    wl4[t + i * 256] = w4[t + i * 256];

  const int row0 = blockIdx.x * BR;
  const int colg = t & 7;
  const int rowg = t >> 3;

  float acc[8][8];
#pragma unroll
  for (int i = 0; i < 8; ++i)
#pragma unroll
    for (int j = 0; j < 8; ++j) acc[i][j] = 0.f;

  for (int kc = 0; kc < NDIN; kc += KC) {
    __syncthreads();
#pragma unroll
    for (int p = 0; p < 4; ++p) {
      const int i = t + p * 256;
      const int r = i >> 2;
      const int c4 = i & 3;
      const int grow = row0 + r;
      float4 v = (grow < n_nodes)
                     ? *(const float4*)(x + (size_t)grow * NDIN + kc + c4 * 4)
                     : make_float4(0.f, 0.f, 0.f, 0.f);
      xt[c4 * 4 + 0][r] = v.x;
      xt[c4 * 4 + 1][r] = v.y;
      xt[c4 * 4 + 2][r] = v.z;
      xt[c4 * 4 + 3][r] = v.w;
    }
    __syncthreads();
#pragma unroll
    for (int k = 0; k < KC; ++k) {
      const float4 a0 = *(const float4*)(&xt[k][rowg * 8]);
      const float4 a1 = *(const float4*)(&xt[k][rowg * 8 + 4]);
      const float4 b0 = *(const float4*)(&wlds[kc + k][colg * 8]);
      const float4 b1 = *(const float4*)(&wlds[kc + k][colg * 8 + 4]);
      const float a[8] = {a0.x, a0.y, a0.z, a0.w, a1.x, a1.y, a1.z, a1.w};
      const float b[8] = {b0.x, b0.y, b0.z, b0.w, b1.x, b1.y, b1.z, b1.w};
#pragma unroll
      for (int i = 0; i < 8; ++i)
#pragma unroll
        for (int j = 0; j < 8; ++j) acc[i][j] += a[i] * b[j];
    }
  }
#pragma unroll
  for (int i = 0; i < 8; ++i) {
    const int grow = row0 + rowg * 8 + i;
    if (grow < n_nodes) {
      __hip_bfloat16 tmp[8];
#pragma unroll
      for (int j = 0; j < 8; ++j) tmp[j] = __float2bfloat16(acc[i][j]);
      *(uint4*)(xw + (size_t)grow * NDOUT + colg * 8) = *(const uint4*)tmp;
    }
  }
}

// ---------------------------------------------------------------------------
// Exclusive scan of partial (nbuck*HB ints, bucket-major) -> sc
// ---------------------------------------------------------------------------
__global__ __launch_bounds__(1024) void scan_block_kernel(
    const int* __restrict__ partial, int* __restrict__ sc,
    int* __restrict__ bsums, int n) {
  __shared__ int s[1024];
  const int t = threadIdx.x;
  const int i = blockIdx.x * 1024 + t;
  const int v = (i < n) ? partial[i] : 0;
  s[t] = v;
  __syncthreads();
#pragma unroll
  for (int off = 1; off < 1024; off <<= 1) {
    int add = (t >= off) ? s[t - off] : 0;
    __syncthreads();
    s[t] += add;
    __syncthreads();
  }
  if (i < n) sc[i] = s[t] - v;  // exclusive
  if (t == 1023) bsums[blockIdx.x] = s[1023];
}

__global__ __launch_bounds__(1024) void scan_tops_kernel(int* __restrict__ bsums,
                                                         int nb) {
  __shared__ int s[1024];
  const int t = threadIdx.x;
  const int v = (t < nb) ? bsums[t] : 0;
  s[t] = v;
  __syncthreads();
#pragma unroll
  for (int off = 1; off < 1024; off <<= 1) {
    int add = (t >= off) ? s[t - off] : 0;
    __syncthreads();
    s[t] += add;
    __syncthreads();
  }
  if (t < nb) bsums[t] = s[t] - v;
}

__global__ __launch_bounds__(256) void add_off_kernel(
    int* __restrict__ sc, const int* __restrict__ bsums, int n) {
  const int i = blockIdx.x * 256 + threadIdx.x;
  if (i < n) sc[i] += bsums[i >> 10];
}

// ---------------------------------------------------------------------------
// K3: place (proven in round 12). LDS int-atomic slot cursors; scattered 8B
// stores land bucket-grouped. NO global atomics.
// ---------------------------------------------------------------------------
__global__ __launch_bounds__(256) void place_kernel(
    const int* __restrict__ src, const int* __restrict__ dst,
    const float* __restrict__ ew, const int* __restrict__ sc,
    int2* __restrict__ bins, int n_edges, int nbuck, int ch) {
  __shared__ int lbase[NBUCK_MAX];
  const int t = threadIdx.x;
  const int hb = blockIdx.x;
  for (int i = t; i < nbuck; i += 256) lbase[i] = sc[(size_t)i * HB + hb];
  __syncthreads();
  const int e0 = hb * ch;
  const int e1 = min(e0 + ch, n_edges);
  for (int e = e0 + t * 4; e < e1; e += 256 * 4) {
    if (e + 4 <= e1) {
      const int4 s4 = *(const int4*)(src + e);
      const int4 d4 = *(const int4*)(dst + e);
      const float4 w4 = *(const float4*)(ew + e);
      const int p0 = atomicAdd(&lbase[s4.x >> BSH], 1);
      const int p1 = atomicAdd(&lbase[s4.y >> BSH], 1);
      const int p2 = atomicAdd(&lbase[s4.z >> BSH], 1);
      const int p3 = atomicAdd(&lbase[s4.w >> BSH], 1);
      bins[p0] = make_int2(d4.x | ((s4.x & 63) << 20), __float_as_int(w4.x));
      bins[p1] = make_int2(d4.y | ((s4.y & 63) << 20), __float_as_int(w4.y));
      bins[p2] = make_int2(d4.z | ((s4.z & 63) << 20), __float_as_int(w4.z));
      bins[p3] = make_int2(d4.w | ((s4.w & 63) << 20), __float_as_int(w4.w));
    } else {
      for (int k = e; k < e1; ++k) {
        const int s = src[k];
        const int p = atomicAdd(&lbase[s >> BSH], 1);
        bins[p] = make_int2(dst[k] | ((s & 63) << 20), __float_as_int(ew[k]));
      }
    }
  }
}

// ---------------------------------------------------------------------------
// K4: bucket_agg. One block per 64-node bucket. Per CAP-edge chunk:
//   count (LDS int atomics, native) -> 64-wide LDS scan -> node-sorted place
//   into LDS ebuf -> each wave OWNS nodes wv+4k and accumulates in REGISTERS.
// Zero float atomics anywhere. ebuf reads are wave-broadcast. Chunk loop
// handles arbitrarily large buckets. ReLU fused, coalesced writes.
// ---------------------------------------------------------------------------
__global__ __launch_bounds__(256) void bucket_agg_kernel(
    const __hip_bfloat16* __restrict__ xw, const int2* __restrict__ bins,
    const int* __restrict__ sc, float* __restrict__ out, int n_nodes,
    int n_edges, int nbuck) {
  __shared__ int2 ebuf[CAP];        // 16 KB
  __shared__ int cnt[BNODES];
  __shared__ int offs[BNODES];      // inclusive scan of cnt
  __shared__ int cursor[BNODES];
  const int t = threadIdx.x;
  const int b = blockIdx.x;
  const int start = sc[(size_t)b * HB];
  const int end = (b == nbuck - 1) ? n_edges : sc[(size_t)(b + 1) * HB];
  const int lane = t & 63;
  const int wv = t >> 6;

  float acc[16];
#pragma unroll
  for (int k = 0; k < 16; ++k) acc[k] = 0.f;

  for (int cbase = start; cbase < end; cbase += CAP) {
    const int ccnt = min(CAP, end - cbase);
    if (t < BNODES) cnt[t] = 0;
    __syncthreads();
    // sweep 1: count tags
    for (int i = t; i < ccnt; i += 256)
      atomicAdd(&cnt[(bins[cbase + i].x >> 20) & 63], 1);
    __syncthreads();
    if (t < BNODES) offs[t] = cnt[t];
    __syncthreads();
#pragma unroll
    for (int d = 1; d < BNODES; d <<= 1) {
      int v = 0;
      if (t < BNODES && t >= d) v = offs[t - d];
      __syncthreads();
      if (t < BNODES) offs[t] += v;
      __syncthreads();
    }
    if (t < BNODES) cursor[t] = offs[t] - cnt[t];
    __syncthreads();
    // sweep 2: node-sorted place into LDS
    for (int i = t; i < ccnt; i += 256) {
      const int2 bb = bins[cbase + i];
      const int tag = (bb.x >> 20) & 63;
      const int slot = atomicAdd(&cursor[tag], 1);
      ebuf[slot] = make_int2(bb.x & DMASK, bb.y);
    }
    __syncthreads();
    // aggregate: wave wv owns nodes r = wv + 4k
    for (int k = 0; k < 16; ++k) {
      const int r = wv + (k << 2);
      const int s1 = offs[r];
      const int s0 = s1 - cnt[r];
      float a = acc[k];
      int i = s0;
      for (; i + 8 <= s1; i += 8) {
        int2 bb[8];
#pragma unroll
        for (int j = 0; j < 8; ++j) bb[j] = ebuf[i + j];
        float v[8];
#pragma unroll
        for (int j = 0; j < 8; ++j)
          v[j] = __bfloat162float(xw[(size_t)bb[j].x * NDOUT + lane]);
#pragma unroll
        for (int j = 0; j < 8; ++j) a += __int_as_float(bb[j].y) * v[j];
      }
      for (; i < s1; ++i) {
        const int2 bb = ebuf[i];
        a += __int_as_float(bb.y) *
             __bfloat162float(xw[(size_t)bb.x * NDOUT + lane]);
      }
      acc[k] = a;
    }
    __syncthreads();  // ebuf reuse guard
  }

#pragma unroll
  for (int k = 0; k < 16; ++k) {
    const int gnode = b * BNODES + wv + (k << 2);
    if (gnode < n_nodes)
      out[(size_t)gnode * NDOUT + lane] = fmaxf(acc[k], 0.f);
  }
}

// ---------------------------------------------------------------------------
// Fallback path (ws too small / shape out of range): atomic scatter + relu
// ---------------------------------------------------------------------------
__global__ __launch_bounds__(256) void edge_scatter_kernel(
    const __hip_bfloat16* __restrict__ xw, const float* __restrict__ ew,
    const int* __restrict__ src, const int* __restrict__ dst,
    float* __restrict__ out, int n_edges) {
  const int lane = threadIdx.x & 63;
  const int wid = (blockIdx.x * 256 + threadIdx.x) >> 6;
  const int nw = (gridDim.x * 256) >> 6;
  for (int e0 = wid * 4; e0 < n_edges; e0 += nw * 4) {
    int s[4];
    float v[4];
    bool ok[4];
#pragma unroll
    for (int j = 0; j < 4; ++j) {
      const int e = e0 + j;
      ok[j] = (e < n_edges);
      const int ee = ok[j] ? e : 0;
      s[j] = src[ee];
      v[j] = __bfloat162float(xw[(size_t)dst[ee] * NDOUT + lane]) * ew[ee];
    }
#pragma unroll
    for (int j = 0; j < 4; ++j) {
      if (ok[j]) unsafeAtomicAdd(out + (size_t)s[j] * NDOUT + lane, v[j]);
    }
  }
}

__global__ __launch_bounds__(256) void relu_kernel(float* __restrict__ out,
                                                   int n4) {
  float4* o4 = (float4*)out;
  int i = blockIdx.x * 256 + threadIdx.x;
  const int stride = gridDim.x * 256;
  for (; i < n4; i += stride) {
    float4 v = o4[i];
    v.x = fmaxf(v.x, 0.f);
    v.y = fmaxf(v.y, 0.f);
    v.z = fmaxf(v.z, 0.f);
    v.w = fmaxf(v.w, 0.f);
    o4[i] = v;
  }
}

extern "C" void kernel_launch(void* const* d_in, const int* in_sizes, int n_in,
                              void* d_out, int out_size, void* d_ws,
                              size_t ws_size, hipStream_t stream) {
  const float* x = (const float*)d_in[0];     // [N, 128]
  const float* ew = (const float*)d_in[1];    // [E]
  const float* w = (const float*)d_in[2];     // [128, 64]
  const int* esrc = (const int*)d_in[3];      // [E]
  const int* edst = (const int*)d_in[4];      // [E]
  float* out = (float*)d_out;                 // [N, 64]

  const int n_nodes = in_sizes[0] / NDIN;
  const int n_edges = in_sizes[1];
  const int nbuck = (n_nodes + BNODES - 1) >> BSH;
  const int ch = (((n_edges + HB - 1) / HB) + 3) & ~3;  // 4-aligned chunk
  const int nscan = nbuck * HB;

  // ws layout:
  //   xw:      N*64 bf16
  //   bins:    E int2  ({dst | (src&63)<<20, ew})
  //   partial: nbuck*HB int
  //   sc:      nbuck*HB int
  //   bsums:   1024 int
  char* base = (char*)d_ws;
  size_t off = 0;
  __hip_bfloat16* xw = (__hip_bfloat16*)(base + off);
  off += (size_t)n_nodes * NDOUT * 2;
  off = (off + 15) & ~(size_t)15;
  int2* bins = (int2*)(base + off); off += (size_t)n_edges * 8;
  int* partial = (int*)(base + off); off += (size_t)nscan * 4;
  int* sc = (int*)(base + off); off += (size_t)nscan * 4;
  int* bsums = (int*)(base + off); off += 4096;
  const bool csr_ok =
      (ws_size >= off) && (nbuck <= NBUCK_MAX) && (n_nodes <= DMASK);

  const int gblocks = (n_nodes + BR - 1) / BR;

  if (csr_ok) {
    // 1) fused GEMM + bucket-hist (no global atomics anywhere)
    gemm_hist_kernel<<<gblocks + HB, 256, 0, stream>>>(
        x, w, xw, n_nodes, gblocks, esrc, partial, n_edges, nbuck, ch);
    // 2) scan partials -> segment bases
    const int nb = (nscan + 1023) / 1024;
    scan_block_kernel<<<nb, 1024, 0, stream>>>(partial, sc, bsums, nscan);
    scan_tops_kernel<<<1, 1024, 0, stream>>>(bsums, nb);
    add_off_kernel<<<(nscan + 255) / 256, 256, 0, stream>>>(sc, bsums, nscan);
    // 3) place into bucket-grouped bins (LDS-int-atomic slots)
    place_kernel<<<HB, 256, 0, stream>>>(esrc, edst, ew, sc, bins, n_edges,
                                         nbuck, ch);
    // 4) per-bucket node-sort + register-accumulate aggregate + ReLU
    bucket_agg_kernel<<<nbuck, 256, 0, stream>>>(xw, bins, sc, out, n_nodes,
                                                 n_edges, nbuck);
  } else {
    gemm_hist_kernel<<<gblocks, 256, 0, stream>>>(
        x, w, xw, n_nodes, gblocks, esrc, (int*)d_out, n_edges, 0, ch);
    hipMemsetAsync(d_out, 0, (size_t)out_size * sizeof(float), stream);
    edge_scatter_kernel<<<2048, 256, 0, stream>>>(xw, ew, esrc, edst, out,
                                                  n_edges);
    relu_kernel<<<1024, 256, 0, stream>>>(out, out_size / 4);
  }
}